// Round 1
// baseline (1790.865 us; speedup 1.0000x reference)
//
#include <hip/hip_runtime.h>

// Problem constants
constexpr int NN   = 50000;
constexpr int EE   = 800000;
constexpr int FIN  = 64;
constexpr int EDIM = 16;
constexpr int HDIM = 128;
constexpr int GG   = 256;
constexpr float BN_EPS_C = 1e-5f;

// ---------------------------------------------------------------------------
// Edge phase: aggr[dst] += relu(X[src] + edge_attr @ ew + eb)
// Block = 256 threads = (256/CIN) edges x CIN features. Grid-stride so the
// LDS staging of ew (16 x CIN) amortizes over many edges.
// ---------------------------------------------------------------------------
template <int CIN>
__global__ __launch_bounds__(256) void edge_kernel(
    const float* __restrict__ X, const float* __restrict__ ea,
    const int* __restrict__ ei, const float* __restrict__ ew,
    const float* __restrict__ eb, float* __restrict__ aggr)
{
    __shared__ float ew_s[EDIM * CIN + CIN];
    for (int i = threadIdx.x; i < EDIM * CIN; i += 256) ew_s[i] = ew[i];
    for (int i = threadIdx.x; i < CIN; i += 256) ew_s[EDIM * CIN + i] = eb[i];
    __syncthreads();

    constexpr int EPB = 256 / CIN;
    const int eg = threadIdx.x / CIN;
    const int j  = threadIdx.x % CIN;

    for (int base = blockIdx.x * EPB; base < EE; base += gridDim.x * EPB) {
        const int e = base + eg;
        if (e < EE) {
            const int s = ei[e];
            const int d = ei[EE + e];
            float acc = ew_s[EDIM * CIN + j];
#pragma unroll
            for (int k = 0; k < EDIM; ++k)
                acc = fmaf(ea[(long long)e * EDIM + k], ew_s[k * CIN + j], acc);
            float m = X[(long long)s * CIN + j] + acc;
            m = fmaxf(m, 0.0f);
            unsafeAtomicAdd(&aggr[(long long)d * CIN + j], m);
        }
    }
}

// ---------------------------------------------------------------------------
// MLP part 1: T = relu((A + Xin) @ W1 + b1). Thread-per-node, register h,
// weight loads are wave-uniform -> scalar loads. blockIdx.y splits the 128
// output features into 2 halves for more grid parallelism.
// ---------------------------------------------------------------------------
template <int CIN>
__global__ __launch_bounds__(256) void mlp1_kernel(
    const float* __restrict__ A, const float* __restrict__ Xin,
    const float* __restrict__ w1, const float* __restrict__ b1,
    float* __restrict__ T)
{
    const int n = blockIdx.x * 256 + threadIdx.x;
    if (n >= NN) return;
    const int jofs = blockIdx.y * (HDIM / 2);

    float h[CIN];
#pragma unroll
    for (int k = 0; k < CIN; ++k)
        h[k] = A[(long long)n * CIN + k] + Xin[(long long)n * CIN + k];

    for (int j = jofs; j < jofs + HDIM / 2; ++j) {
        float a0 = 0.f, a1 = 0.f, a2 = 0.f, a3 = 0.f;
#pragma unroll
        for (int k = 0; k < CIN; k += 4) {
            a0 = fmaf(h[k],     w1[(k)     * HDIM + j], a0);
            a1 = fmaf(h[k + 1], w1[(k + 1) * HDIM + j], a1);
            a2 = fmaf(h[k + 2], w1[(k + 2) * HDIM + j], a2);
            a3 = fmaf(h[k + 3], w1[(k + 3) * HDIM + j], a3);
        }
        float acc = b1[j] + ((a0 + a1) + (a2 + a3));
        T[(long long)n * HDIM + j] = fmaxf(acc, 0.0f);
    }
}

// ---------------------------------------------------------------------------
// MLP part 2: Y = T @ W2 + b2
// ---------------------------------------------------------------------------
__global__ __launch_bounds__(256) void mlp2_kernel(
    const float* __restrict__ T, const float* __restrict__ w2,
    const float* __restrict__ b2, float* __restrict__ Y)
{
    const int n = blockIdx.x * 256 + threadIdx.x;
    if (n >= NN) return;
    const int jofs = blockIdx.y * (HDIM / 2);

    float t[HDIM];
#pragma unroll
    for (int k = 0; k < HDIM; ++k) t[k] = T[(long long)n * HDIM + k];

    for (int j = jofs; j < jofs + HDIM / 2; ++j) {
        float a0 = 0.f, a1 = 0.f, a2 = 0.f, a3 = 0.f;
#pragma unroll
        for (int k = 0; k < HDIM; k += 4) {
            a0 = fmaf(t[k],     w2[(k)     * HDIM + j], a0);
            a1 = fmaf(t[k + 1], w2[(k + 1) * HDIM + j], a1);
            a2 = fmaf(t[k + 2], w2[(k + 2) * HDIM + j], a2);
            a3 = fmaf(t[k + 3], w2[(k + 3) * HDIM + j], a3);
        }
        Y[(long long)n * HDIM + j] = b2[j] + ((a0 + a1) + (a2 + a3));
    }
}

// ---------------------------------------------------------------------------
// BN stats: per-feature sum and sumsq over all N rows.
// thread j = feature, 2 rows in flight per block iteration.
// ---------------------------------------------------------------------------
__global__ __launch_bounds__(256) void stats_kernel(
    const float* __restrict__ Y, float* __restrict__ stats)
{
    const int j = threadIdx.x & (HDIM - 1);
    const int half = threadIdx.x >> 7;
    float s = 0.f, q = 0.f;
    for (int n = blockIdx.x * 2 + half; n < NN; n += gridDim.x * 2) {
        float v = Y[(long long)n * HDIM + j];
        s += v;
        q = fmaf(v, v, q);
    }
    unsafeAtomicAdd(&stats[j], s);
    unsafeAtomicAdd(&stats[HDIM + j], q);
}

// ---------------------------------------------------------------------------
// BN apply + relu (+ optional fused pooling atomics for last layer)
// ---------------------------------------------------------------------------
template <bool POOL>
__global__ __launch_bounds__(256) void bnrelu_kernel(
    const float* __restrict__ Y, const float* __restrict__ stats,
    const float* __restrict__ g, const float* __restrict__ b,
    float* __restrict__ X, const int* __restrict__ batch,
    float* __restrict__ pooled)
{
    const long long total = (long long)NN * HDIM;
    for (long long i = (long long)blockIdx.x * 256 + threadIdx.x; i < total;
         i += (long long)gridDim.x * 256) {
        const int j = (int)(i & (HDIM - 1));
        const int n = (int)(i >> 7);
        const float inv_n = 1.0f / (float)NN;
        float mu  = stats[j] * inv_n;
        float var = stats[HDIM + j] * inv_n - mu * mu;
        float sc  = g[j] * rsqrtf(fmaxf(var, 0.0f) + BN_EPS_C);
        float v   = fmaxf((Y[i] - mu) * sc + b[j], 0.0f);
        X[i] = v;
        if (POOL) unsafeAtomicAdd(&pooled[(long long)batch[n] * HDIM + j], v);
    }
}

__global__ __launch_bounds__(256) void counts_kernel(
    const int* __restrict__ batch, float* __restrict__ counts)
{
    const int n = blockIdx.x * 256 + threadIdx.x;
    if (n < NN) unsafeAtomicAdd(&counts[batch[n]], 1.0f);
}

// out[g] = (pooled[g]/count[g]) . lin_w + lin_b
__global__ __launch_bounds__(128) void final_kernel(
    const float* __restrict__ pooled, const float* __restrict__ counts,
    const float* __restrict__ lw, const float* __restrict__ lb,
    float* __restrict__ out)
{
    __shared__ float red[2];
    const int gid = blockIdx.x;
    const int j = threadIdx.x;
    float c = fmaxf(counts[gid], 1.0f);
    float v = pooled[(long long)gid * HDIM + j] / c * lw[j];
    for (int o = 32; o > 0; o >>= 1) v += __shfl_down(v, o, 64);
    if ((j & 63) == 0) red[j >> 6] = v;
    __syncthreads();
    if (j == 0) out[gid] = red[0] + red[1] + lb[0];
}

// ---------------------------------------------------------------------------
extern "C" void kernel_launch(void* const* d_in, const int* in_sizes, int n_in,
                              void* d_out, int out_size, void* d_ws, size_t ws_size,
                              hipStream_t stream)
{
    const float* x     = (const float*)d_in[0];
    const float* ea    = (const float*)d_in[1];
    const int*   ei    = (const int*)d_in[2];
    const int*   batch = (const int*)d_in[3];

    // per-layer params: e_w, e_b, m_w1, m_b1, m_w2, m_b2, bn_g, bn_b
    const float* ew[3]  = {(const float*)d_in[4],  (const float*)d_in[12], (const float*)d_in[20]};
    const float* ebv[3] = {(const float*)d_in[5],  (const float*)d_in[13], (const float*)d_in[21]};
    const float* w1[3]  = {(const float*)d_in[6],  (const float*)d_in[14], (const float*)d_in[22]};
    const float* b1[3]  = {(const float*)d_in[7],  (const float*)d_in[15], (const float*)d_in[23]};
    const float* w2[3]  = {(const float*)d_in[8],  (const float*)d_in[16], (const float*)d_in[24]};
    const float* b2[3]  = {(const float*)d_in[9],  (const float*)d_in[17], (const float*)d_in[25]};
    const float* bng[3] = {(const float*)d_in[10], (const float*)d_in[18], (const float*)d_in[26]};
    const float* bnb[3] = {(const float*)d_in[11], (const float*)d_in[19], (const float*)d_in[27]};
    const float* linw = (const float*)d_in[28];
    const float* linb = (const float*)d_in[29];

    // workspace layout (floats)
    float* A      = (float*)d_ws;            // N*128 (aggr, then reused as Y)
    float* X      = A + (size_t)NN * HDIM;   // N*128 (features between layers)
    float* T      = X + (size_t)NN * HDIM;   // N*128 (mlp hidden)
    float* stats  = T + (size_t)NN * HDIM;   // 3 * 256
    float* pooled = stats + 3 * 2 * HDIM;    // G*128
    float* counts = pooled + (size_t)GG * HDIM; // G

    // zero accumulators (stats..counts contiguous)
    hipMemsetAsync(stats, 0, (3 * 2 * HDIM + GG * HDIM + GG) * sizeof(float), stream);

    const dim3 mgrid((NN + 255) / 256, 2);

    // ---- Layer 1 (cin = 64, input = x) ----
    hipMemsetAsync(A, 0, (size_t)NN * FIN * sizeof(float), stream);
    edge_kernel<FIN><<<2048, 256, 0, stream>>>(x, ea, ei, ew[0], ebv[0], A);
    mlp1_kernel<FIN><<<mgrid, 256, 0, stream>>>(A, x, w1[0], b1[0], T);
    mlp2_kernel<<<mgrid, 256, 0, stream>>>(T, w2[0], b2[0], A);
    stats_kernel<<<512, 256, 0, stream>>>(A, stats);
    bnrelu_kernel<false><<<2048, 256, 0, stream>>>(A, stats, bng[0], bnb[0], X, batch, pooled);

    // ---- Layer 2 (cin = 128, input = X) ----
    hipMemsetAsync(A, 0, (size_t)NN * HDIM * sizeof(float), stream);
    edge_kernel<HDIM><<<2048, 256, 0, stream>>>(X, ea, ei, ew[1], ebv[1], A);
    mlp1_kernel<HDIM><<<mgrid, 256, 0, stream>>>(A, X, w1[1], b1[1], T);
    mlp2_kernel<<<mgrid, 256, 0, stream>>>(T, w2[1], b2[1], A);
    stats_kernel<<<512, 256, 0, stream>>>(A, stats + 256);
    bnrelu_kernel<false><<<2048, 256, 0, stream>>>(A, stats + 256, bng[1], bnb[1], X, batch, pooled);

    // ---- Layer 3 (cin = 128, input = X, fused pooling) ----
    hipMemsetAsync(A, 0, (size_t)NN * HDIM * sizeof(float), stream);
    edge_kernel<HDIM><<<2048, 256, 0, stream>>>(X, ea, ei, ew[2], ebv[2], A);
    mlp1_kernel<HDIM><<<mgrid, 256, 0, stream>>>(A, X, w1[2], b1[2], T);
    mlp2_kernel<<<mgrid, 256, 0, stream>>>(T, w2[2], b2[2], A);
    stats_kernel<<<512, 256, 0, stream>>>(A, stats + 512);
    bnrelu_kernel<true><<<2048, 256, 0, stream>>>(A, stats + 512, bng[2], bnb[2], X, batch, pooled);

    // ---- Readout ----
    counts_kernel<<<(NN + 255) / 256, 256, 0, stream>>>(batch, counts);
    final_kernel<<<GG, 128, 0, stream>>>(pooled, counts, linw, linb, (float*)d_out);
}

// Round 2
// 1059.482 us; speedup vs baseline: 1.6903x; 1.6903x over previous
//
#include <hip/hip_runtime.h>

typedef unsigned int uint;
typedef unsigned short ushort;

constexpr int NN   = 50000;
constexpr int EE   = 800000;
constexpr int FIN  = 64;
constexpr int EDIM = 16;
constexpr int HDIM = 128;
constexpr int GG   = 256;
constexpr float BN_EPS_C = 1e-5f;

// ===========================================================================
// CSR build: deg histogram -> single-block scan -> scatter (int atomics only)
// ===========================================================================
__global__ __launch_bounds__(256) void deg_kernel(
    const int* __restrict__ ei, uint* __restrict__ deg)
{
    const int e = blockIdx.x * 256 + threadIdx.x;
    if (e < EE) atomicAdd(&deg[ei[EE + e]], 1u);
}

__global__ __launch_bounds__(1024) void scan_kernel(
    const uint* __restrict__ deg, uint* __restrict__ off, uint* __restrict__ cursor)
{
    __shared__ uint ls[1024];
    const int t = threadIdx.x;
    constexpr int CH = (NN + 1023) / 1024;  // 49
    const int b = t * CH;
    const int e = min(b + CH, NN);

    uint mysum = 0;
    for (int i = b; i < e; ++i) mysum += deg[i];
    ls[t] = mysum;
    __syncthreads();
    // Hillis-Steele inclusive scan over 1024
    for (int o = 1; o < 1024; o <<= 1) {
        uint v = (t >= o) ? ls[t - o] : 0u;
        __syncthreads();
        ls[t] += v;
        __syncthreads();
    }
    uint run = ls[t] - mysum;  // exclusive base for this chunk
    for (int i = b; i < e; ++i) {
        off[i] = run; cursor[i] = run;
        run += deg[i];
    }
    if (t == 0) off[NN] = EE;
}

__global__ __launch_bounds__(256) void scatter_kernel(
    const int* __restrict__ ei, uint* __restrict__ cursor,
    ushort* __restrict__ srcs, uint* __restrict__ eidx)
{
    const int e = blockIdx.x * 256 + threadIdx.x;
    if (e < EE) {
        const int d = ei[EE + e];
        const uint pos = atomicAdd(&cursor[d], 1u);
        srcs[pos] = (ushort)ei[e];
        eidx[pos] = (uint)e;
    }
}

// ===========================================================================
// Edge gather: H[n] = X[n] + sum_{e: dst==n} relu(X[src_e] + ea[e] @ ew + eb)
// CIN threads per node; ew column held in 16 VGPRs; one store per element.
// ===========================================================================
template <int CIN>
__global__ __launch_bounds__(256) void gather_kernel(
    const float* __restrict__ X, const float* __restrict__ ea,
    const uint* __restrict__ off, const ushort* __restrict__ srcs,
    const uint* __restrict__ eidx, const float* __restrict__ ew,
    const float* __restrict__ eb, float* __restrict__ Hout)
{
    constexpr int NPB = 256 / CIN;
    const int j  = threadIdx.x & (CIN - 1);
    const int nl = threadIdx.x / CIN;
    const int n  = blockIdx.x * NPB + nl;
    if (n >= NN) return;

    float w[EDIM];
#pragma unroll
    for (int k = 0; k < EDIM; ++k) w[k] = ew[k * CIN + j];
    const float ebj = eb[j];

    const uint o0 = off[n], o1 = off[n + 1];
    float acc = 0.0f;
    for (uint idx = o0; idx < o1; ++idx) {
        const int  s = (int)srcs[idx];
        const uint e = eidx[idx];
        const float4* eap = (const float4*)(ea + (size_t)e * EDIM);
        const float4 a0 = eap[0], a1 = eap[1], a2 = eap[2], a3 = eap[3];
        float lin = ebj;
        lin = fmaf(a0.x, w[0],  lin); lin = fmaf(a0.y, w[1],  lin);
        lin = fmaf(a0.z, w[2],  lin); lin = fmaf(a0.w, w[3],  lin);
        lin = fmaf(a1.x, w[4],  lin); lin = fmaf(a1.y, w[5],  lin);
        lin = fmaf(a1.z, w[6],  lin); lin = fmaf(a1.w, w[7],  lin);
        lin = fmaf(a2.x, w[8],  lin); lin = fmaf(a2.y, w[9],  lin);
        lin = fmaf(a2.z, w[10], lin); lin = fmaf(a2.w, w[11], lin);
        lin = fmaf(a3.x, w[12], lin); lin = fmaf(a3.y, w[13], lin);
        lin = fmaf(a3.z, w[14], lin); lin = fmaf(a3.w, w[15], lin);
        acc += fmaxf(X[(size_t)s * CIN + j] + lin, 0.0f);
    }
    Hout[(size_t)n * CIN + j] = acc + X[(size_t)n * CIN + j];
}

// ===========================================================================
// Fused MLP: Y = relu(H @ W1 + b1) @ W2 + b2, in-place capable (Y may == H),
// with fused BN-stats (sum, sumsq per feature) accumulated via atomics.
// 64-node tile, 256 threads, 8 nodes x 4 cols per thread, k-unroll 2.
// ===========================================================================
template <int K>
__global__ __launch_bounds__(256) void mlp_kernel(
    const float* __restrict__ H,
    const float* __restrict__ w1, const float* __restrict__ b1,
    const float* __restrict__ w2, const float* __restrict__ b2,
    float* __restrict__ Y, float* __restrict__ stats)
{
    __shared__ float Hs[64][K];
    __shared__ float Ts[64][HDIM];

    const int t   = threadIdx.x;
    const int nb0 = blockIdx.x * 64;

    // stage H tile (zero-fill rows past NN)
    {
        constexpr int V = 64 * K / 4 / 256;  // float4s per thread
        const float4* src = (const float4*)(H + (size_t)nb0 * K);
        float4* dst = (float4*)(&Hs[0][0]);
#pragma unroll
        for (int i = 0; i < V; ++i) {
            const int i4 = t + 256 * i;
            const int node = nb0 + (i4 * 4) / K;
            float4 v = make_float4(0.f, 0.f, 0.f, 0.f);
            if (node < NN) v = src[i4];
            dst[i4] = v;
        }
    }
    __syncthreads();

    const int tx = t & 31, ty = t >> 5;
    const int jc = tx * 4;
    const int nb = ty * 8;

    float acc[8][4];
#pragma unroll
    for (int i = 0; i < 8; ++i)
#pragma unroll
        for (int c = 0; c < 4; ++c) acc[i][c] = 0.0f;

    for (int k = 0; k < K; k += 2) {
        const float4 wa = *(const float4*)&w1[(k)     * HDIM + jc];
        const float4 wb = *(const float4*)&w1[(k + 1) * HDIM + jc];
#pragma unroll
        for (int i = 0; i < 8; ++i) {
            const float2 h2 = *(const float2*)&Hs[nb + i][k];
            acc[i][0] = fmaf(h2.x, wa.x, acc[i][0]);
            acc[i][1] = fmaf(h2.x, wa.y, acc[i][1]);
            acc[i][2] = fmaf(h2.x, wa.z, acc[i][2]);
            acc[i][3] = fmaf(h2.x, wa.w, acc[i][3]);
            acc[i][0] = fmaf(h2.y, wb.x, acc[i][0]);
            acc[i][1] = fmaf(h2.y, wb.y, acc[i][1]);
            acc[i][2] = fmaf(h2.y, wb.z, acc[i][2]);
            acc[i][3] = fmaf(h2.y, wb.w, acc[i][3]);
        }
    }
    {
        const float4 bb = *(const float4*)&b1[jc];
#pragma unroll
        for (int i = 0; i < 8; ++i) {
            float4 v;
            v.x = fmaxf(acc[i][0] + bb.x, 0.f);
            v.y = fmaxf(acc[i][1] + bb.y, 0.f);
            v.z = fmaxf(acc[i][2] + bb.z, 0.f);
            v.w = fmaxf(acc[i][3] + bb.w, 0.f);
            *(float4*)&Ts[nb + i][jc] = v;
        }
    }
    __syncthreads();

#pragma unroll
    for (int i = 0; i < 8; ++i)
#pragma unroll
        for (int c = 0; c < 4; ++c) acc[i][c] = 0.0f;

    for (int k = 0; k < HDIM; k += 2) {
        const float4 wa = *(const float4*)&w2[(k)     * HDIM + jc];
        const float4 wb = *(const float4*)&w2[(k + 1) * HDIM + jc];
#pragma unroll
        for (int i = 0; i < 8; ++i) {
            const float2 h2 = *(const float2*)&Ts[nb + i][k];
            acc[i][0] = fmaf(h2.x, wa.x, acc[i][0]);
            acc[i][1] = fmaf(h2.x, wa.y, acc[i][1]);
            acc[i][2] = fmaf(h2.x, wa.z, acc[i][2]);
            acc[i][3] = fmaf(h2.x, wa.w, acc[i][3]);
            acc[i][0] = fmaf(h2.y, wb.x, acc[i][0]);
            acc[i][1] = fmaf(h2.y, wb.y, acc[i][1]);
            acc[i][2] = fmaf(h2.y, wb.z, acc[i][2]);
            acc[i][3] = fmaf(h2.y, wb.w, acc[i][3]);
        }
    }

    // epilogue: bias, store Y, per-thread stats partials
    float sp[4] = {0.f, 0.f, 0.f, 0.f};
    float qp[4] = {0.f, 0.f, 0.f, 0.f};
    {
        const float4 bb = *(const float4*)&b2[jc];
#pragma unroll
        for (int i = 0; i < 8; ++i) {
            const int node = nb0 + nb + i;
            if (node < NN) {
                float4 y;
                y.x = acc[i][0] + bb.x;
                y.y = acc[i][1] + bb.y;
                y.z = acc[i][2] + bb.z;
                y.w = acc[i][3] + bb.w;
                *(float4*)&Y[(size_t)node * HDIM + jc] = y;
                sp[0] += y.x; qp[0] = fmaf(y.x, y.x, qp[0]);
                sp[1] += y.y; qp[1] = fmaf(y.y, y.y, qp[1]);
                sp[2] += y.z; qp[2] = fmaf(y.z, y.z, qp[2]);
                sp[3] += y.w; qp[3] = fmaf(y.w, y.w, qp[3]);
            }
        }
    }
    __syncthreads();  // Ts reads done -> reuse as reduction scratch
    float* rs = &Ts[0][0];          // [8][128]
    float* rq = &Ts[0][0] + 1024;   // [8][128]
#pragma unroll
    for (int c = 0; c < 4; ++c) {
        rs[ty * HDIM + jc + c] = sp[c];
        rq[ty * HDIM + jc + c] = qp[c];
    }
    __syncthreads();
    if (t < HDIM) {
        float ss = 0.f, qq = 0.f;
#pragma unroll
        for (int r = 0; r < 8; ++r) {
            ss += rs[r * HDIM + t];
            qq += rq[r * HDIM + t];
        }
        unsafeAtomicAdd(&stats[t], ss);
        unsafeAtomicAdd(&stats[HDIM + t], qq);
    }
}

// ===========================================================================
// BN apply + relu (elementwise, float4)
// ===========================================================================
__global__ __launch_bounds__(256) void bnrelu_kernel(
    const float* __restrict__ Y, const float* __restrict__ stats,
    const float* __restrict__ g, const float* __restrict__ b,
    float* __restrict__ Xo)
{
    constexpr int TOT4 = NN * (HDIM / 4);
    constexpr float inv_n = 1.0f / (float)NN;
    for (int i = blockIdx.x * 256 + threadIdx.x; i < TOT4; i += gridDim.x * 256) {
        const int j4 = i & (HDIM / 4 - 1);
        const float4 y  = ((const float4*)Y)[i];
        const float4 su = ((const float4*)stats)[j4];
        const float4 sq = ((const float4*)(stats + HDIM))[j4];
        const float4 gg = ((const float4*)g)[j4];
        const float4 bb = ((const float4*)b)[j4];
        float4 v;
        {
            float mu = su.x * inv_n, var = sq.x * inv_n - mu * mu;
            v.x = fmaxf((y.x - mu) * (gg.x * rsqrtf(fmaxf(var, 0.f) + BN_EPS_C)) + bb.x, 0.f);
        }
        {
            float mu = su.y * inv_n, var = sq.y * inv_n - mu * mu;
            v.y = fmaxf((y.y - mu) * (gg.y * rsqrtf(fmaxf(var, 0.f) + BN_EPS_C)) + bb.y, 0.f);
        }
        {
            float mu = su.z * inv_n, var = sq.z * inv_n - mu * mu;
            v.z = fmaxf((y.z - mu) * (gg.z * rsqrtf(fmaxf(var, 0.f) + BN_EPS_C)) + bb.z, 0.f);
        }
        {
            float mu = su.w * inv_n, var = sq.w * inv_n - mu * mu;
            v.w = fmaxf((y.w - mu) * (gg.w * rsqrtf(fmaxf(var, 0.f) + BN_EPS_C)) + bb.w, 0.f);
        }
        ((float4*)Xo)[i] = v;
    }
}

// ===========================================================================
// Layer-3 fused: BN+relu + per-graph mean pool + final linear.
// One block (128 threads) per graph; batch is sorted -> binary search bounds.
// ===========================================================================
__global__ __launch_bounds__(128) void poolfinal_kernel(
    const float* __restrict__ Y, const float* __restrict__ stats,
    const float* __restrict__ g, const float* __restrict__ b,
    const int* __restrict__ batch, const float* __restrict__ lw,
    const float* __restrict__ lb, float* __restrict__ out)
{
    __shared__ float red[2];
    const int gid = blockIdx.x;
    const int j = threadIdx.x;

    auto lower_bound = [&](int key) {
        int lo = 0, hi = NN;
        while (lo < hi) { int m = (lo + hi) >> 1; if (batch[m] < key) lo = m + 1; else hi = m; }
        return lo;
    };
    const int s = lower_bound(gid);
    const int e = lower_bound(gid + 1);

    constexpr float inv_n = 1.0f / (float)NN;
    const float mu  = stats[j] * inv_n;
    const float var = stats[HDIM + j] * inv_n - mu * mu;
    const float sc  = g[j] * rsqrtf(fmaxf(var, 0.f) + BN_EPS_C);
    const float sh  = b[j];

    float acc = 0.0f;
    for (int n = s; n < e; ++n)
        acc += fmaxf((Y[(size_t)n * HDIM + j] - mu) * sc + sh, 0.0f);

    const float cnt = fmaxf((float)(e - s), 1.0f);
    float v = acc / cnt * lw[j];
    for (int o = 32; o > 0; o >>= 1) v += __shfl_down(v, o, 64);
    if ((j & 63) == 0) red[j >> 6] = v;
    __syncthreads();
    if (j == 0) out[gid] = red[0] + red[1] + lb[0];
}

// ===========================================================================
extern "C" void kernel_launch(void* const* d_in, const int* in_sizes, int n_in,
                              void* d_out, int out_size, void* d_ws, size_t ws_size,
                              hipStream_t stream)
{
    const float* x     = (const float*)d_in[0];
    const float* ea    = (const float*)d_in[1];
    const int*   ei    = (const int*)d_in[2];
    const int*   batch = (const int*)d_in[3];

    const float* ew[3]  = {(const float*)d_in[4],  (const float*)d_in[12], (const float*)d_in[20]};
    const float* ebv[3] = {(const float*)d_in[5],  (const float*)d_in[13], (const float*)d_in[21]};
    const float* w1[3]  = {(const float*)d_in[6],  (const float*)d_in[14], (const float*)d_in[22]};
    const float* b1[3]  = {(const float*)d_in[7],  (const float*)d_in[15], (const float*)d_in[23]};
    const float* w2[3]  = {(const float*)d_in[8],  (const float*)d_in[16], (const float*)d_in[24]};
    const float* b2[3]  = {(const float*)d_in[9],  (const float*)d_in[17], (const float*)d_in[25]};
    const float* bng[3] = {(const float*)d_in[10], (const float*)d_in[18], (const float*)d_in[26]};
    const float* bnb[3] = {(const float*)d_in[11], (const float*)d_in[19], (const float*)d_in[27]};
    const float* linw = (const float*)d_in[28];
    const float* linb = (const float*)d_in[29];

    // ---- workspace layout ----
    char* p = (char*)d_ws;
    float* bufA = (float*)p;              p += (size_t)NN * HDIM * 4;   // 25.6 MB
    float* bufB = (float*)p;              p += (size_t)NN * HDIM * 4;   // 25.6 MB
    float* stats = (float*)p;             p += 3 * 2 * HDIM * 4;        // 3 KB
    uint* off    = (uint*)p;              p += ((NN + 4) & ~3) * 4;     // off[N+1]
    uint* degcur = (uint*)p;              p += (size_t)NN * 4;          // deg, then cursor
    uint* eidx   = (uint*)p;              p += (size_t)EE * 4;          // 3.2 MB
    ushort* srcs = (ushort*)p;            p += (size_t)EE * 2;          // 1.6 MB

    // ---- build CSR (once; reused by all 3 layers) ----
    hipMemsetAsync(degcur, 0, (size_t)NN * 4, stream);
    hipMemsetAsync(stats, 0, 3 * 2 * HDIM * 4, stream);
    deg_kernel<<<(EE + 255) / 256, 256, 0, stream>>>(ei, degcur);
    scan_kernel<<<1, 1024, 0, stream>>>(degcur, off, degcur);
    scatter_kernel<<<(EE + 255) / 256, 256, 0, stream>>>(ei, degcur, srcs, eidx);

    const int mlp_grid = (NN + 63) / 64;

    // ---- Layer 1 (cin=64): x -> bufA -> bufB(Y) -> bufA(X2) ----
    gather_kernel<FIN><<<(NN + 3) / 4, 256, 0, stream>>>(x, ea, off, srcs, eidx, ew[0], ebv[0], bufA);
    mlp_kernel<FIN><<<mlp_grid, 256, 0, stream>>>(bufA, w1[0], b1[0], w2[0], b2[0], bufB, stats);
    bnrelu_kernel<<<2048, 256, 0, stream>>>(bufB, stats, bng[0], bnb[0], bufA);

    // ---- Layer 2 (cin=128): bufA -> bufB(H) -> bufB(Y, in-place) -> bufA(X3) ----
    gather_kernel<HDIM><<<(NN + 1) / 2, 256, 0, stream>>>(bufA, ea, off, srcs, eidx, ew[1], ebv[1], bufB);
    mlp_kernel<HDIM><<<mlp_grid, 256, 0, stream>>>(bufB, w1[1], b1[1], w2[1], b2[1], bufB, stats + 256);
    bnrelu_kernel<<<2048, 256, 0, stream>>>(bufB, stats + 256, bng[1], bnb[1], bufA);

    // ---- Layer 3 (cin=128): bufA -> bufB(H) -> bufB(Y) -> fused pool+linear ----
    gather_kernel<HDIM><<<(NN + 1) / 2, 256, 0, stream>>>(bufA, ea, off, srcs, eidx, ew[2], ebv[2], bufB);
    mlp_kernel<HDIM><<<mlp_grid, 256, 0, stream>>>(bufB, w1[2], b1[2], w2[2], b2[2], bufB, stats + 512);
    poolfinal_kernel<<<GG, 128, 0, stream>>>(bufB, stats + 512, bng[2], bnb[2], batch, linw, linb, (float*)d_out);
}

// Round 3
// 905.476 us; speedup vs baseline: 1.9778x; 1.1701x over previous
//
#include <hip/hip_runtime.h>

typedef unsigned int uint;

constexpr int NN   = 50000;
constexpr int EE   = 800000;
constexpr int FIN  = 64;
constexpr int EDIM = 16;
constexpr int HDIM = 128;
constexpr int GG   = 256;
constexpr float BN_EPS_C = 1e-5f;

// ===========================================================================
// CSR build
// ===========================================================================
__global__ __launch_bounds__(256) void deg_kernel(
    const int* __restrict__ ei, uint* __restrict__ deg)
{
    const int e = blockIdx.x * 256 + threadIdx.x;
    if (e < EE) atomicAdd(&deg[ei[EE + e]], 1u);
}

__global__ __launch_bounds__(1024) void scan_kernel(
    const uint* __restrict__ deg, uint* __restrict__ off, uint* __restrict__ cursor)
{
    __shared__ uint ls[1024];
    const int t = threadIdx.x;
    constexpr int CH = (NN + 1023) / 1024;  // 49
    const int b = t * CH;
    const int e = min(b + CH, NN);

    uint mysum = 0;
    for (int i = b; i < e; ++i) mysum += deg[i];
    ls[t] = mysum;
    __syncthreads();
    for (int o = 1; o < 1024; o <<= 1) {
        uint v = (t >= o) ? ls[t - o] : 0u;
        __syncthreads();
        ls[t] += v;
        __syncthreads();
    }
    uint run = ls[t] - mysum;
    for (int i = b; i < e; ++i) {
        off[i] = run; cursor[i] = run;
        run += deg[i];
    }
    if (t == 0) off[NN] = EE;
}

// scatter: build srcs (u32) and either ea_perm (CSR-ordered edge_attr rows)
// or eidx (fallback when workspace too small for ea_perm).
template <bool PERM>
__global__ __launch_bounds__(256) void scatter_kernel(
    const int* __restrict__ ei, const float* __restrict__ ea,
    uint* __restrict__ cursor, uint* __restrict__ srcs,
    uint* __restrict__ eidx, float* __restrict__ ea_perm)
{
    const int e = blockIdx.x * 256 + threadIdx.x;
    if (e < EE) {
        const int d = ei[EE + e];
        const uint pos = atomicAdd(&cursor[d], 1u);
        srcs[pos] = (uint)ei[e];
        if (PERM) {
            const float4* s = (const float4*)(ea + (size_t)e * EDIM);
            float4* dst = (float4*)(ea_perm + (size_t)pos * EDIM);
            dst[0] = s[0]; dst[1] = s[1]; dst[2] = s[2]; dst[3] = s[3];
        } else {
            eidx[pos] = (uint)e;
        }
    }
}

// ===========================================================================
// Edge gather: H[n] = X[n] + sum_{e: dst==n} relu(X[src_e] + ea[e] @ ew + eb)
// float4 per lane: CIN/4 lanes per node. ew column block in 64 VGPRs.
// PERM: ea is ea_perm, read sequentially at idx. else: indirect via eidx.
// ===========================================================================
template <int CIN, bool PERM>
__global__ __launch_bounds__(256) void gather_kernel(
    const float* __restrict__ X, const float* __restrict__ ea,
    const uint* __restrict__ off, const uint* __restrict__ srcs,
    const uint* __restrict__ eidx, const float* __restrict__ ew,
    const float* __restrict__ eb, float* __restrict__ Hout)
{
    constexpr int LPN = CIN / 4;       // lanes per node
    constexpr int NPB = 256 / LPN;     // nodes per block
    const int lane = threadIdx.x & (LPN - 1);
    const int nl   = threadIdx.x / LPN;
    const int n    = blockIdx.x * NPB + nl;
    if (n >= NN) return;
    const int j4 = lane * 4;

    float4 w[EDIM];
#pragma unroll
    for (int k = 0; k < EDIM; ++k) w[k] = *(const float4*)&ew[k * CIN + j4];
    const float4 ebv = *(const float4*)&eb[j4];

    const uint o0 = off[n], o1 = off[n + 1];
    float4 acc = make_float4(0.f, 0.f, 0.f, 0.f);

    uint s_cur = (o0 < o1) ? srcs[o0] : 0u;
    for (uint idx = o0; idx < o1; ++idx) {
        const uint s_nxt = (idx + 1 < o1) ? srcs[idx + 1] : 0u;
        const float4* eap = PERM
            ? (const float4*)(ea + (size_t)idx * EDIM)
            : (const float4*)(ea + (size_t)eidx[idx] * EDIM);
        float a[EDIM];
        *(float4*)&a[0]  = eap[0];
        *(float4*)&a[4]  = eap[1];
        *(float4*)&a[8]  = eap[2];
        *(float4*)&a[12] = eap[3];
        const float4 xv = *(const float4*)&X[(size_t)s_cur * CIN + j4];
        float4 lin = ebv;
#pragma unroll
        for (int k = 0; k < EDIM; ++k) {
            lin.x = fmaf(a[k], w[k].x, lin.x);
            lin.y = fmaf(a[k], w[k].y, lin.y);
            lin.z = fmaf(a[k], w[k].z, lin.z);
            lin.w = fmaf(a[k], w[k].w, lin.w);
        }
        acc.x += fmaxf(xv.x + lin.x, 0.f);
        acc.y += fmaxf(xv.y + lin.y, 0.f);
        acc.z += fmaxf(xv.z + lin.z, 0.f);
        acc.w += fmaxf(xv.w + lin.w, 0.f);
        s_cur = s_nxt;
    }
    const float4 self = *(const float4*)&X[(size_t)n * CIN + j4];
    float4 outv;
    outv.x = acc.x + self.x;
    outv.y = acc.y + self.y;
    outv.z = acc.z + self.z;
    outv.w = acc.w + self.w;
    *(float4*)&Hout[(size_t)n * CIN + j4] = outv;
}

// ===========================================================================
// Fused MLP: Y = relu(H @ W1 + b1) @ W2 + b2 (+ fused BN stats)
// ===========================================================================
template <int K>
__global__ __launch_bounds__(256) void mlp_kernel(
    const float* __restrict__ H,
    const float* __restrict__ w1, const float* __restrict__ b1,
    const float* __restrict__ w2, const float* __restrict__ b2,
    float* __restrict__ Y, float* __restrict__ stats)
{
    __shared__ float Hs[64][K];
    __shared__ float Ts[64][HDIM];

    const int t   = threadIdx.x;
    const int nb0 = blockIdx.x * 64;

    {
        constexpr int V = 64 * K / 4 / 256;
        const float4* src = (const float4*)(H + (size_t)nb0 * K);
        float4* dst = (float4*)(&Hs[0][0]);
#pragma unroll
        for (int i = 0; i < V; ++i) {
            const int i4 = t + 256 * i;
            const int node = nb0 + (i4 * 4) / K;
            float4 v = make_float4(0.f, 0.f, 0.f, 0.f);
            if (node < NN) v = src[i4];
            dst[i4] = v;
        }
    }
    __syncthreads();

    const int tx = t & 31, ty = t >> 5;
    const int jc = tx * 4;
    const int nb = ty * 8;

    float acc[8][4];
#pragma unroll
    for (int i = 0; i < 8; ++i)
#pragma unroll
        for (int c = 0; c < 4; ++c) acc[i][c] = 0.0f;

    for (int k = 0; k < K; k += 2) {
        const float4 wa = *(const float4*)&w1[(k)     * HDIM + jc];
        const float4 wb = *(const float4*)&w1[(k + 1) * HDIM + jc];
#pragma unroll
        for (int i = 0; i < 8; ++i) {
            const float2 h2 = *(const float2*)&Hs[nb + i][k];
            acc[i][0] = fmaf(h2.x, wa.x, acc[i][0]);
            acc[i][1] = fmaf(h2.x, wa.y, acc[i][1]);
            acc[i][2] = fmaf(h2.x, wa.z, acc[i][2]);
            acc[i][3] = fmaf(h2.x, wa.w, acc[i][3]);
            acc[i][0] = fmaf(h2.y, wb.x, acc[i][0]);
            acc[i][1] = fmaf(h2.y, wb.y, acc[i][1]);
            acc[i][2] = fmaf(h2.y, wb.z, acc[i][2]);
            acc[i][3] = fmaf(h2.y, wb.w, acc[i][3]);
        }
    }
    {
        const float4 bb = *(const float4*)&b1[jc];
#pragma unroll
        for (int i = 0; i < 8; ++i) {
            float4 v;
            v.x = fmaxf(acc[i][0] + bb.x, 0.f);
            v.y = fmaxf(acc[i][1] + bb.y, 0.f);
            v.z = fmaxf(acc[i][2] + bb.z, 0.f);
            v.w = fmaxf(acc[i][3] + bb.w, 0.f);
            *(float4*)&Ts[nb + i][jc] = v;
        }
    }
    __syncthreads();

#pragma unroll
    for (int i = 0; i < 8; ++i)
#pragma unroll
        for (int c = 0; c < 4; ++c) acc[i][c] = 0.0f;

    for (int k = 0; k < HDIM; k += 2) {
        const float4 wa = *(const float4*)&w2[(k)     * HDIM + jc];
        const float4 wb = *(const float4*)&w2[(k + 1) * HDIM + jc];
#pragma unroll
        for (int i = 0; i < 8; ++i) {
            const float2 h2 = *(const float2*)&Ts[nb + i][k];
            acc[i][0] = fmaf(h2.x, wa.x, acc[i][0]);
            acc[i][1] = fmaf(h2.x, wa.y, acc[i][1]);
            acc[i][2] = fmaf(h2.x, wa.z, acc[i][2]);
            acc[i][3] = fmaf(h2.x, wa.w, acc[i][3]);
            acc[i][0] = fmaf(h2.y, wb.x, acc[i][0]);
            acc[i][1] = fmaf(h2.y, wb.y, acc[i][1]);
            acc[i][2] = fmaf(h2.y, wb.z, acc[i][2]);
            acc[i][3] = fmaf(h2.y, wb.w, acc[i][3]);
        }
    }

    float sp[4] = {0.f, 0.f, 0.f, 0.f};
    float qp[4] = {0.f, 0.f, 0.f, 0.f};
    {
        const float4 bb = *(const float4*)&b2[jc];
#pragma unroll
        for (int i = 0; i < 8; ++i) {
            const int node = nb0 + nb + i;
            if (node < NN) {
                float4 y;
                y.x = acc[i][0] + bb.x;
                y.y = acc[i][1] + bb.y;
                y.z = acc[i][2] + bb.z;
                y.w = acc[i][3] + bb.w;
                *(float4*)&Y[(size_t)node * HDIM + jc] = y;
                sp[0] += y.x; qp[0] = fmaf(y.x, y.x, qp[0]);
                sp[1] += y.y; qp[1] = fmaf(y.y, y.y, qp[1]);
                sp[2] += y.z; qp[2] = fmaf(y.z, y.z, qp[2]);
                sp[3] += y.w; qp[3] = fmaf(y.w, y.w, qp[3]);
            }
        }
    }
    __syncthreads();
    float* rs = &Ts[0][0];
    float* rq = &Ts[0][0] + 1024;
#pragma unroll
    for (int c = 0; c < 4; ++c) {
        rs[ty * HDIM + jc + c] = sp[c];
        rq[ty * HDIM + jc + c] = qp[c];
    }
    __syncthreads();
    if (t < HDIM) {
        float ss = 0.f, qq = 0.f;
#pragma unroll
        for (int r = 0; r < 8; ++r) {
            ss += rs[r * HDIM + t];
            qq += rq[r * HDIM + t];
        }
        unsafeAtomicAdd(&stats[t], ss);
        unsafeAtomicAdd(&stats[HDIM + t], qq);
    }
}

// ===========================================================================
// BN apply + relu
// ===========================================================================
__global__ __launch_bounds__(256) void bnrelu_kernel(
    const float* __restrict__ Y, const float* __restrict__ stats,
    const float* __restrict__ g, const float* __restrict__ b,
    float* __restrict__ Xo)
{
    constexpr int TOT4 = NN * (HDIM / 4);
    constexpr float inv_n = 1.0f / (float)NN;
    for (int i = blockIdx.x * 256 + threadIdx.x; i < TOT4; i += gridDim.x * 256) {
        const int j4 = i & (HDIM / 4 - 1);
        const float4 y  = ((const float4*)Y)[i];
        const float4 su = ((const float4*)stats)[j4];
        const float4 sq = ((const float4*)(stats + HDIM))[j4];
        const float4 gg = ((const float4*)g)[j4];
        const float4 bb = ((const float4*)b)[j4];
        float4 v;
        {
            float mu = su.x * inv_n, var = sq.x * inv_n - mu * mu;
            v.x = fmaxf((y.x - mu) * (gg.x * rsqrtf(fmaxf(var, 0.f) + BN_EPS_C)) + bb.x, 0.f);
        }
        {
            float mu = su.y * inv_n, var = sq.y * inv_n - mu * mu;
            v.y = fmaxf((y.y - mu) * (gg.y * rsqrtf(fmaxf(var, 0.f) + BN_EPS_C)) + bb.y, 0.f);
        }
        {
            float mu = su.z * inv_n, var = sq.z * inv_n - mu * mu;
            v.z = fmaxf((y.z - mu) * (gg.z * rsqrtf(fmaxf(var, 0.f) + BN_EPS_C)) + bb.z, 0.f);
        }
        {
            float mu = su.w * inv_n, var = sq.w * inv_n - mu * mu;
            v.w = fmaxf((y.w - mu) * (gg.w * rsqrtf(fmaxf(var, 0.f) + BN_EPS_C)) + bb.w, 0.f);
        }
        ((float4*)Xo)[i] = v;
    }
}

// ===========================================================================
// Layer-3 fused: BN+relu + per-graph mean pool + final linear.
// ===========================================================================
__global__ __launch_bounds__(128) void poolfinal_kernel(
    const float* __restrict__ Y, const float* __restrict__ stats,
    const float* __restrict__ g, const float* __restrict__ b,
    const int* __restrict__ batch, const float* __restrict__ lw,
    const float* __restrict__ lb, float* __restrict__ out)
{
    __shared__ float red[2];
    const int gid = blockIdx.x;
    const int j = threadIdx.x;

    auto lower_bound = [&](int key) {
        int lo = 0, hi = NN;
        while (lo < hi) { int m = (lo + hi) >> 1; if (batch[m] < key) lo = m + 1; else hi = m; }
        return lo;
    };
    const int s = lower_bound(gid);
    const int e = lower_bound(gid + 1);

    constexpr float inv_n = 1.0f / (float)NN;
    const float mu  = stats[j] * inv_n;
    const float var = stats[HDIM + j] * inv_n - mu * mu;
    const float sc  = g[j] * rsqrtf(fmaxf(var, 0.f) + BN_EPS_C);
    const float sh  = b[j];

    float acc = 0.0f;
    for (int n = s; n < e; ++n)
        acc += fmaxf((Y[(size_t)n * HDIM + j] - mu) * sc + sh, 0.0f);

    const float cnt = fmaxf((float)(e - s), 1.0f);
    float v = acc / cnt * lw[j];
    for (int o = 32; o > 0; o >>= 1) v += __shfl_down(v, o, 64);
    if ((j & 63) == 0) red[j >> 6] = v;
    __syncthreads();
    if (j == 0) out[gid] = red[0] + red[1] + lb[0];
}

// ===========================================================================
extern "C" void kernel_launch(void* const* d_in, const int* in_sizes, int n_in,
                              void* d_out, int out_size, void* d_ws, size_t ws_size,
                              hipStream_t stream)
{
    const float* x     = (const float*)d_in[0];
    const float* ea    = (const float*)d_in[1];
    const int*   ei    = (const int*)d_in[2];
    const int*   batch = (const int*)d_in[3];

    const float* ew[3]  = {(const float*)d_in[4],  (const float*)d_in[12], (const float*)d_in[20]};
    const float* ebv[3] = {(const float*)d_in[5],  (const float*)d_in[13], (const float*)d_in[21]};
    const float* w1[3]  = {(const float*)d_in[6],  (const float*)d_in[14], (const float*)d_in[22]};
    const float* b1[3]  = {(const float*)d_in[7],  (const float*)d_in[15], (const float*)d_in[23]};
    const float* w2[3]  = {(const float*)d_in[8],  (const float*)d_in[16], (const float*)d_in[24]};
    const float* b2[3]  = {(const float*)d_in[9],  (const float*)d_in[17], (const float*)d_in[25]};
    const float* bng[3] = {(const float*)d_in[10], (const float*)d_in[18], (const float*)d_in[26]};
    const float* bnb[3] = {(const float*)d_in[11], (const float*)d_in[19], (const float*)d_in[27]};
    const float* linw = (const float*)d_in[28];
    const float* linb = (const float*)d_in[29];

    // ---- workspace layout ----
    char* p = (char*)d_ws;
    float* bufA  = (float*)p;  p += (size_t)NN * HDIM * 4;
    float* bufB  = (float*)p;  p += (size_t)NN * HDIM * 4;
    float* stats = (float*)p;  p += 3 * 2 * HDIM * 4;
    uint* off    = (uint*)p;   p += ((NN + 4) & ~3) * 4;
    uint* degcur = (uint*)p;   p += (size_t)NN * 4;
    uint* srcs   = (uint*)p;   p += (size_t)EE * 4;
    // tail: either ea_perm (E*16 f32) or eidx (E u32)
    const size_t used_base = (size_t)(p - (char*)d_ws);
    const bool use_perm = ws_size >= used_base + (size_t)EE * EDIM * 4;
    float* ea_perm = (float*)p;
    uint*  eidx    = (uint*)p;

    hipMemsetAsync(degcur, 0, (size_t)NN * 4, stream);
    hipMemsetAsync(stats, 0, 3 * 2 * HDIM * 4, stream);
    deg_kernel<<<(EE + 255) / 256, 256, 0, stream>>>(ei, degcur);
    scan_kernel<<<1, 1024, 0, stream>>>(degcur, off, degcur);
    if (use_perm)
        scatter_kernel<true><<<(EE + 255) / 256, 256, 0, stream>>>(ei, ea, degcur, srcs, eidx, ea_perm);
    else
        scatter_kernel<false><<<(EE + 255) / 256, 256, 0, stream>>>(ei, ea, degcur, srcs, eidx, ea_perm);

    const int mlp_grid = (NN + 63) / 64;
    const int g64  = (NN * (FIN  / 4) + 255) / 256;  // grid for cin=64 gather
    const int g128 = (NN * (HDIM / 4) + 255) / 256;  // grid for cin=128 gather

    if (use_perm) {
        gather_kernel<FIN, true><<<g64, 256, 0, stream>>>(x, ea_perm, off, srcs, eidx, ew[0], ebv[0], bufA);
        mlp_kernel<FIN><<<mlp_grid, 256, 0, stream>>>(bufA, w1[0], b1[0], w2[0], b2[0], bufB, stats);
        bnrelu_kernel<<<2048, 256, 0, stream>>>(bufB, stats, bng[0], bnb[0], bufA);

        gather_kernel<HDIM, true><<<g128, 256, 0, stream>>>(bufA, ea_perm, off, srcs, eidx, ew[1], ebv[1], bufB);
        mlp_kernel<HDIM><<<mlp_grid, 256, 0, stream>>>(bufB, w1[1], b1[1], w2[1], b2[1], bufB, stats + 256);
        bnrelu_kernel<<<2048, 256, 0, stream>>>(bufB, stats + 256, bng[1], bnb[1], bufA);

        gather_kernel<HDIM, true><<<g128, 256, 0, stream>>>(bufA, ea_perm, off, srcs, eidx, ew[2], ebv[2], bufB);
        mlp_kernel<HDIM><<<mlp_grid, 256, 0, stream>>>(bufB, w1[2], b1[2], w2[2], b2[2], bufB, stats + 512);
        poolfinal_kernel<<<GG, 128, 0, stream>>>(bufB, stats + 512, bng[2], bnb[2], batch, linw, linb, (float*)d_out);
    } else {
        gather_kernel<FIN, false><<<g64, 256, 0, stream>>>(x, ea, off, srcs, eidx, ew[0], ebv[0], bufA);
        mlp_kernel<FIN><<<mlp_grid, 256, 0, stream>>>(bufA, w1[0], b1[0], w2[0], b2[0], bufB, stats);
        bnrelu_kernel<<<2048, 256, 0, stream>>>(bufB, stats, bng[0], bnb[0], bufA);

        gather_kernel<HDIM, false><<<g128, 256, 0, stream>>>(bufA, ea, off, srcs, eidx, ew[1], ebv[1], bufB);
        mlp_kernel<HDIM><<<mlp_grid, 256, 0, stream>>>(bufB, w1[1], b1[1], w2[1], b2[1], bufB, stats + 256);
        bnrelu_kernel<<<2048, 256, 0, stream>>>(bufB, stats + 256, bng[1], bnb[1], bufA);

        gather_kernel<HDIM, false><<<g128, 256, 0, stream>>>(bufA, ea, off, srcs, eidx, ew[2], ebv[2], bufB);
        mlp_kernel<HDIM><<<mlp_grid, 256, 0, stream>>>(bufB, w1[2], b1[2], w2[2], b2[2], bufB, stats + 512);
        poolfinal_kernel<<<GG, 128, 0, stream>>>(bufB, stats + 512, bng[2], bnb[2], batch, linw, linb, (float*)d_out);
    }
}